// Round 18
// 2278.135 us; speedup vs baseline: 10.0637x; 1.0927x over previous
//
#include <hip/hip_runtime.h>
#include <cmath>

// MoR forward, round 18 = round 17 (passing, 2.49 ms) with ONE staging change:
// reg-staged LDS fills (uint2 -> VGPR -> ds_write) in gemm_bf3 + lmhead_fast
// -> __builtin_amdgcn_global_load_lds width=16 (guide ladder: 517 -> 874 TF).
// Swizzle handled per rule #21: LINEAR LDS dest + INVERSE-swizzled per-lane
// global source + swizzled reads. Inverse map: at linear L (=wavebase+lane*16),
// r=L>>7, inner=L&127, kc0*8 = inner ^ ((r&7)<<4) (XOR hits bits 4-6 only, so
// each 16B line = one contiguous 16B global chunk). LDS image bit-identical.

constexpr int kB = 2, kS = 2048, kD = 1024, kH = 16, kKV = 4, kDH = 64,
              kFI = 2816, kV = 32000, kT = kB * kS;
constexpr size_t kBtOff  = 114688000;
constexpr size_t kAbfOff = 112590848;
constexpr size_t kXOff   = 108396544;
constexpr int kR1 = 3456;
constexpr int kQKV = 1536;               // 1024 q | 256 k | 256 v
constexpr int kGU = 5632;                // 2816 g | 2816 u

typedef __attribute__((ext_vector_type(8))) __bf16 bf16x8;
typedef __attribute__((ext_vector_type(4))) float f32x4;
typedef unsigned short u16;
typedef unsigned int u32;

__device__ inline u32 f2bf1(float f) {   // RTN-even bf16, low 16 bits
  u32 u = __builtin_bit_cast(u32, f);
  return (u + 0x7FFFu + ((u >> 16) & 1u)) >> 16;
}
__device__ inline void splitbf(float v, u32& h, u32& l) {
  h = f2bf1(v);
  float hf = __builtin_bit_cast(float, h << 16);
  l = f2bf1(v - hf);                     // v-hf exact (Sterbenz)
}
__device__ inline int xcd_remap(int hb, int nwg) {
  int q = nwg >> 3, r = nwg & 7;
  int xcd = hb & 7, pos = hb >> 3;
  int start = (xcd < r) ? xcd * (q + 1) : r * (q + 1) + (xcd - r) * q;
  return start + pos;
}

// Stage one 16KB [128 rows x 64k bf16] tile: linear gload_lds dest + inverse-
// swizzled global source. Produces the SAME LDS image as the old swizzled
// ds_write path (reads stay swizzled). 4 issues per wave (256-thr block).
__device__ inline void stage_lds16(const u16* __restrict__ gbase, int K,
                                   int row0, int k0, char* ldsbase, int t) {
  int w = t >> 6, lane = t & 63;
#pragma unroll
  for (int i = 0; i < 4; ++i) {
    int wb = (w * 4 + i) * 1024;          // wave-uniform LDS base
    int L = wb + lane * 16;               // this lane's linear dest
    int r = L >> 7, inner = L & 127;
    int kc0 = (inner ^ ((r & 7) << 4)) >> 3;   // even; 16B contiguous chunk
    const u16* g = gbase + (size_t)(row0 + r) * K + k0 + kc0 * 4;
    __builtin_amdgcn_global_load_lds(
        (const __attribute__((address_space(1))) u32*)g,
        (__attribute__((address_space(3))) u32*)(ldsbase + wb), 16, 0, 0);
  }
}

// ---------------- RoPE tables -----------------------------------------------
__global__ __launch_bounds__(256) void tables_kernel(float* __restrict__ cosT,
                                                     float* __restrict__ sinT) {
  int tid = blockIdx.x * 256 + threadIdx.x;
  int t = tid >> 5, d = tid & 31;
  float inv = (float)pow(10000.0, -(double)d / 32.0);
  float fr = (float)t * inv;
  cosT[tid] = (float)cos((double)fr);
  sinT[tid] = (float)sin((double)fr);
}

__global__ void init_kernel(int* __restrict__ mask, float* __restrict__ aux) {
  int t = threadIdx.x;
  for (int e = t; e < kT; e += 256) mask[e] = 1;
  if (t == 0) aux[0] = 0.f;
}

__global__ __launch_bounds__(256) void embed_kernel(const int* __restrict__ ids,
    const float* __restrict__ emb, float* __restrict__ x) {
  int tid = blockIdx.x * 256 + threadIdx.x;
  int token = tid >> 8;
  int c4 = (tid & 255) << 2;
  int id = ids[token];
  *(float4*)&x[(size_t)token * kD + c4] =
      *(const float4*)&emb[(size_t)id * kD + c4];
}

// ---------------- compact active-token index list (ascending) ----------------
__global__ __launch_bounds__(1024) void scan_kernel(const int* __restrict__ mask,
    int* __restrict__ cidx, int keep, int keepR) {
  __shared__ int sv[1024];
  int t = threadIdx.x;
  int base = t * 4;
  int loc[4];
  int c = 0;
#pragma unroll
  for (int j = 0; j < 4; ++j) { loc[j] = c; c += mask[base + j]; }
  sv[t] = c;
  __syncthreads();
  for (int off = 1; off < 1024; off <<= 1) {
    int v = (t >= off) ? sv[t - off] : 0;
    __syncthreads();
    sv[t] += v;
    __syncthreads();
  }
  int pre = (t == 0) ? 0 : sv[t - 1];
#pragma unroll
  for (int j = 0; j < 4; ++j)
    if (mask[base + j]) cidx[pre + loc[j]] = base + j;
  __syncthreads();
  for (int e = keep + t; e < keepR; e += 1024) cidx[e] = 0;  // dummy pad
}

// ---------------- RMSNorm with fused hi/lo split (full rows) -----------------
__global__ __launch_bounds__(256) void rmsnorm_split_kernel(
    const float* __restrict__ x, const float* __restrict__ w,
    u16* __restrict__ ohi, u16* __restrict__ olo) {
  int tok = blockIdx.x, t = threadIdx.x;
  const float* xr = x + (size_t)tok * kD;
  float4 xv = *(const float4*)&xr[t * 4];
  float s = xv.x * xv.x + xv.y * xv.y + xv.z * xv.z + xv.w * xv.w;
#pragma unroll
  for (int off = 1; off < 64; off <<= 1) s += __shfl_xor(s, off);
  __shared__ float red[4];
  if ((t & 63) == 0) red[t >> 6] = s;
  __syncthreads();
  float tot = red[0] + red[1] + red[2] + red[3];
  float sc = 1.f / sqrtf(tot * (1.f / kD) + 1e-6f);
  float4 wv = *(const float4*)&w[t * 4];
  float o0 = xv.x * sc * wv.x, o1 = xv.y * sc * wv.y;
  float o2 = xv.z * sc * wv.z, o3 = xv.w * sc * wv.w;
  u32 h0, h1, h2, h3, l0, l1, l2, l3;
  splitbf(o0, h0, l0); splitbf(o1, h1, l1);
  splitbf(o2, h2, l2); splitbf(o3, h3, l3);
  uint2 ph, pl;
  ph.x = h0 | (h1 << 16); ph.y = h2 | (h3 << 16);
  pl.x = l0 | (l1 << 16); pl.y = l2 | (l3 << 16);
  *(uint2*)&ohi[(size_t)tok * kD + t * 4] = ph;
  *(uint2*)&olo[(size_t)tok * kD + t * 4] = pl;
}

// ---------------- RMSNorm + split, GATHERED (compact rows) -------------------
__global__ __launch_bounds__(256) void rmsnorm_split_gather(
    const float* __restrict__ x, const float* __restrict__ w,
    const int* __restrict__ cidx, u16* __restrict__ ohi, u16* __restrict__ olo) {
  int row = blockIdx.x, t = threadIdx.x;
  int tok = cidx[row];
  const float* xr = x + (size_t)tok * kD;
  float4 xv = *(const float4*)&xr[t * 4];
  float s = xv.x * xv.x + xv.y * xv.y + xv.z * xv.z + xv.w * xv.w;
#pragma unroll
  for (int off = 1; off < 64; off <<= 1) s += __shfl_xor(s, off);
  __shared__ float red[4];
  if ((t & 63) == 0) red[t >> 6] = s;
  __syncthreads();
  float tot = red[0] + red[1] + red[2] + red[3];
  float sc = 1.f / sqrtf(tot * (1.f / kD) + 1e-6f);
  float4 wv = *(const float4*)&w[t * 4];
  float o0 = xv.x * sc * wv.x, o1 = xv.y * sc * wv.y;
  float o2 = xv.z * sc * wv.z, o3 = xv.w * sc * wv.w;
  u32 h0, h1, h2, h3, l0, l1, l2, l3;
  splitbf(o0, h0, l0); splitbf(o1, h1, l1);
  splitbf(o2, h2, l2); splitbf(o3, h3, l3);
  uint2 ph, pl;
  ph.x = h0 | (h1 << 16); ph.y = h2 | (h3 << 16);
  pl.x = l0 | (l1 << 16); pl.y = l2 | (l3 << 16);
  *(uint2*)&ohi[(size_t)row * kD + t * 4] = ph;
  *(uint2*)&olo[(size_t)row * kD + t * 4] = pl;
}

// ---------------- final rmsnorm + fn scale -> bf16 A for lm_head -------------
__global__ __launch_bounds__(256) void finalnorm_conv(const float* __restrict__ x,
    const float* __restrict__ fnw, u16* __restrict__ Abf) {
  int tok = blockIdx.x, t = threadIdx.x;
  const float* xr = x + (size_t)tok * kD;
  float4 xv = *(const float4*)&xr[t * 4];
  float s = xv.x * xv.x + xv.y * xv.y + xv.z * xv.z + xv.w * xv.w;
#pragma unroll
  for (int off = 1; off < 64; off <<= 1) s += __shfl_xor(s, off);
  __shared__ float red[4];
  if ((t & 63) == 0) red[t >> 6] = s;
  __syncthreads();
  float tot = red[0] + red[1] + red[2] + red[3];
  float sc = 1.f / sqrtf(tot * (1.f / kD) + 1e-6f);
  float4 wv = *(const float4*)&fnw[t * 4];
  uint2 ph;
  ph.x = f2bf1(xv.x * sc * wv.x) | (f2bf1(xv.y * sc * wv.y) << 16);
  ph.y = f2bf1(xv.z * sc * wv.z) | (f2bf1(xv.w * sc * wv.w) << 16);
  *(uint2*)&Abf[(size_t)tok * kD + t * 4] = ph;
}

// ---------------- router (f64 accumulate) ------------------------------------
__global__ __launch_bounds__(64) void router_kernel(const float* __restrict__ x,
    const float* __restrict__ rw, float* __restrict__ scores) {
  int tok = blockIdx.x, lane = threadIdx.x;
  const float* xr = x + (size_t)tok * kD;
  double s = 0.0;
#pragma unroll
  for (int e = 0; e < kD / 64; ++e)
    s += (double)xr[lane + e * 64] * (double)rw[lane + e * 64];
#pragma unroll
  for (int off = 1; off < 64; off <<= 1) s += __shfl_xor(s, off);
  if (lane == 0) {
    float z = (float)s;
    scores[tok] = 1.f / (1.f + expf(-z));
  }
}

// ---------------- exact top-k (bitonic, ties -> lower index) -----------------
__global__ __launch_bounds__(1024) void topk_kernel(const float* __restrict__ scores,
    int* __restrict__ mask, float* __restrict__ aux, int keep) {
  __shared__ float sv[kT];
  __shared__ int si[kT];
  __shared__ float red[16];
  int t = threadIdx.x;
  for (int e = t; e < kT; e += 1024) {
    sv[e] = mask[e] ? scores[e] : -INFINITY;
    si[e] = e;
  }
  __syncthreads();
  for (int k = 2; k <= kT; k <<= 1) {
    for (int j = k >> 1; j > 0; j >>= 1) {
      for (int e = t; e < kT; e += 1024) {
        int p = e ^ j;
        if (p > e) {
          float v1 = sv[e], v2 = sv[p];
          int i1 = si[e], i2 = si[p];
          bool before = (v1 > v2) || (v1 == v2 && i1 < i2);
          bool desc = ((e & k) == 0);
          if (desc ? !before : before) {
            sv[e] = v2; sv[p] = v1; si[e] = i2; si[p] = i1;
          }
        }
      }
      __syncthreads();
    }
  }
  for (int e = t; e < kT; e += 1024) mask[si[e]] = (e < keep) ? 1 : 0;
  float ps = 0.f;
  for (int e = t; e < keep; e += 1024) ps += sv[e];
#pragma unroll
  for (int off = 1; off < 64; off <<= 1) ps += __shfl_xor(ps, off);
  if ((t & 63) == 0) red[t >> 6] = ps;
  __syncthreads();
  if (t == 0) {
    float tot = 0.f;
    for (int i = 0; i < 16; ++i) tot += red[i];
    aux[0] += -(tot / (float)keep) * 1e-3f;
  }
}

// ---------------- RoPE with fused bf16 hi/lo split, fused-QKV input ----------
__global__ __launch_bounds__(256) void rope_split_kernel(
    const float* __restrict__ qkv,
    const float* __restrict__ cosT, const float* __restrict__ sinT,
    u16* __restrict__ Qh, u16* __restrict__ Ql,
    u16* __restrict__ Kh, u16* __restrict__ Kl) {
  int tid = blockIdx.x * 256 + threadIdx.x;
  const int QP = kT * kH * 32;
  const float* base;
  u16 *oh, *ol;
  size_t outoff;
  int token, d;
  if (tid < QP) {
    token = tid >> 9;
    int r = tid & 511;
    int hh = r >> 5; d = r & 31;
    base = qkv + (size_t)token * kQKV + hh * kDH;
    outoff = (size_t)token * (kH * kDH) + hh * kDH;
    oh = Qh; ol = Ql;
  } else {
    int p = tid - QP;
    token = p >> 7;
    int r = p & 127;
    int hh = r >> 5; d = r & 31;
    base = qkv + (size_t)token * kQKV + 1024 + hh * kDH;
    outoff = (size_t)token * (kKV * kDH) + hh * kDH;
    oh = Kh; ol = Kl;
  }
  int s = token & (kS - 1);
  float c = cosT[s * 32 + d], sn = sinT[s * 32 + d];
  float x1 = base[d], x2 = base[d + 32];
  float v1 = x1 * c - x2 * sn;
  float v2 = x2 * c + x1 * sn;
  u32 h1, l1, h2, l2;
  splitbf(v1, h1, l1);
  splitbf(v2, h2, l2);
  oh[outoff + d] = (u16)h1;      ol[outoff + d] = (u16)l1;
  oh[outoff + d + 32] = (u16)h2; ol[outoff + d + 32] = (u16)l2;
}

// ---------------- V transpose-split from fused qkv (v at col 1280) -----------
__global__ __launch_bounds__(256) void vtsplit_kernel(const float* __restrict__ qkv,
    u16* __restrict__ Th, u16* __restrict__ Tl) {
  int ktile = blockIdx.x, kv = blockIdx.y, b = blockIdx.z;
  __shared__ float T[64][65];
  int t = threadIdx.x;
#pragma unroll
  for (int p = 0; p < 16; ++p) {
    int idx = t + p * 256;
    int key = idx >> 6, d = idx & 63;
    T[key][d] =
        qkv[(size_t)(b * kS + ktile * 64 + key) * kQKV + 1280 + kv * kDH + d];
  }
  __syncthreads();
  int dr = t >> 2, kg = t & 3;
  size_t ob = ((size_t)(b * kKV + kv) * kDH + dr) * kS + ktile * 64 + kg * 16;
#pragma unroll
  for (int i = 0; i < 4; ++i) {
    int kk = kg * 16 + i * 4;
    u32 h0, h1, h2, h3, l0, l1, l2, l3;
    splitbf(T[kk + 0][dr], h0, l0); splitbf(T[kk + 1][dr], h1, l1);
    splitbf(T[kk + 2][dr], h2, l2); splitbf(T[kk + 3][dr], h3, l3);
    uint2 ph, pl;
    ph.x = h0 | (h1 << 16); ph.y = h2 | (h3 << 16);
    pl.x = l0 | (l1 << 16); pl.y = l2 | (l3 << 16);
    *(uint2*)&Th[ob + i * 4] = ph;
    *(uint2*)&Tl[ob + i * 4] = pl;
  }
}

// ---------------- MFMA flash attention (bf16x3 QK + PV) ----------------------
__global__ __launch_bounds__(256) void attn_mfma(
    const u16* __restrict__ Qh, const u16* __restrict__ Ql,
    const u16* __restrict__ Kh2, const u16* __restrict__ Kl2,
    const u16* __restrict__ VTh, const u16* __restrict__ VTl,
    u16* __restrict__ ctxH, u16* __restrict__ ctxL) {
  int qb = (int)gridDim.x - 1 - (int)blockIdx.x;  // heaviest first
  int q0 = qb * 64, hh = blockIdx.y, b = blockIdx.z;
  int t = threadIdx.x;
  int lane = t & 63, w = t >> 6;
  int kvh = hh >> 2;
  __shared__ __align__(16) char sQh[8192], sQl[8192];
  __shared__ __align__(16) char sKh[8192], sKl[8192];
  __shared__ __align__(16) char sVh[8192], sVl[8192];
  __shared__ __align__(16) char sPh[8192], sPl[8192];
#pragma unroll
  for (int p = 0; p < 4; ++p) {
    int idx = t + p * 256;
    int r = idx >> 4, kc = idx & 15;
    int off = r * 128 + ((kc * 8) ^ ((r & 7) << 4));
    size_t gq = (size_t)(b * kS + q0 + r) * (kH * kDH) + hh * kDH + kc * 4;
    *(uint2*)(sQh + off) = *(const uint2*)&Qh[gq];
    *(uint2*)(sQl + off) = *(const uint2*)&Ql[gq];
  }
  f32x4 ctxa[4];
#pragma unroll
  for (int i = 0; i < 4; ++i) ctxa[i] = {0.f, 0.f, 0.f, 0.f};
  float lsum[4] = {0.f, 0.f, 0.f, 0.f};
  int ntiles = qb + 1;
  for (int kt = 0; kt < ntiles; ++kt) {
    __syncthreads();
#pragma unroll
    for (int p = 0; p < 4; ++p) {
      int idx = t + p * 256;
      int r = idx >> 4, kc = idx & 15;
      int off = r * 128 + ((kc * 8) ^ ((r & 7) << 4));
      size_t gk = (size_t)(b * kS + kt * 64 + r) * (kKV * kDH) + kvh * kDH + kc * 4;
      size_t gv = ((size_t)(b * kKV + kvh) * kDH + r) * kS + kt * 64 + kc * 4;
      *(uint2*)(sKh + off) = *(const uint2*)&Kh2[gk];
      *(uint2*)(sKl + off) = *(const uint2*)&Kl2[gk];
      *(uint2*)(sVh + off) = *(const uint2*)&VTh[gv];
      *(uint2*)(sVl + off) = *(const uint2*)&VTl[gv];
    }
    __syncthreads();
    f32x4 sf[4];
#pragma unroll
    for (int i = 0; i < 4; ++i) sf[i] = {0.f, 0.f, 0.f, 0.f};
#pragma unroll
    for (int ks = 0; ks < 2; ++ks) {
      int m = w * 16 + (lane & 15);
      int kb = ks * 64 + ((lane >> 4) << 4);
      int ao = m * 128 + (kb ^ ((m & 7) << 4));
      bf16x8 qh8 = *(bf16x8*)(sQh + ao);
      bf16x8 ql8 = *(bf16x8*)(sQl + ao);
#pragma unroll
      for (int nf = 0; nf < 4; ++nf) {
        int n = nf * 16 + (lane & 15);
        int bo = n * 128 + (kb ^ ((n & 7) << 4));
        bf16x8 kh8 = *(bf16x8*)(sKh + bo);
        bf16x8 kl8 = *(bf16x8*)(sKl + bo);
        sf[nf] = __builtin_amdgcn_mfma_f32_16x16x32_bf16(qh8, kh8, sf[nf], 0, 0, 0);
        sf[nf] = __builtin_amdgcn_mfma_f32_16x16x32_bf16(qh8, kl8, sf[nf], 0, 0, 0);
        sf[nf] = __builtin_amdgcn_mfma_f32_16x16x32_bf16(ql8, kh8, sf[nf], 0, 0, 0);
      }
    }
    int qrow = (lane >> 4) << 2;
#pragma unroll
    for (int nf = 0; nf < 4; ++nf) {
      int key = kt * 64 + nf * 16 + (lane & 15);
#pragma unroll
      for (int rg = 0; rg < 4; ++rg) {
        int query = q0 + w * 16 + qrow + rg;
        float p = 0.f;
        if (key <= query) p = __expf(sf[nf][rg] * 0.125f);
        lsum[rg] += p;
        u32 ph, pl;
        splitbf(p, ph, pl);
        int ql_ = w * 16 + qrow + rg;
        int kl_ = nf * 16 + (lane & 15);
        int po = ql_ * 128 + ((kl_ * 2) ^ ((ql_ & 7) << 4));
        *(u16*)(sPh + po) = (u16)ph;
        *(u16*)(sPl + po) = (u16)pl;
      }
    }
#pragma unroll
    for (int ks = 0; ks < 2; ++ks) {
      int m = w * 16 + (lane & 15);
      int kb = ks * 64 + ((lane >> 4) << 4);
      int ao = m * 128 + (kb ^ ((m & 7) << 4));
      bf16x8 ph8 = *(bf16x8*)(sPh + ao);
      bf16x8 pl8 = *(bf16x8*)(sPl + ao);
#pragma unroll
      for (int nf = 0; nf < 4; ++nf) {
        int n = nf * 16 + (lane & 15);
        int bo = n * 128 + (kb ^ ((n & 7) << 4));
        bf16x8 vh8 = *(bf16x8*)(sVh + bo);
        bf16x8 vl8 = *(bf16x8*)(sVl + bo);
        ctxa[nf] = __builtin_amdgcn_mfma_f32_16x16x32_bf16(ph8, vh8, ctxa[nf], 0, 0, 0);
        ctxa[nf] = __builtin_amdgcn_mfma_f32_16x16x32_bf16(ph8, vl8, ctxa[nf], 0, 0, 0);
        ctxa[nf] = __builtin_amdgcn_mfma_f32_16x16x32_bf16(pl8, vh8, ctxa[nf], 0, 0, 0);
      }
    }
  }
#pragma unroll
  for (int rg = 0; rg < 4; ++rg) {
    float ps = lsum[rg];
    ps += __shfl_xor(ps, 1); ps += __shfl_xor(ps, 2);
    ps += __shfl_xor(ps, 4); ps += __shfl_xor(ps, 8);
    lsum[rg] = ps;
  }
#pragma unroll
  for (int nf = 0; nf < 4; ++nf) {
    int d = nf * 16 + (lane & 15);
#pragma unroll
    for (int rg = 0; rg < 4; ++rg) {
      int query = q0 + w * 16 + ((lane >> 4) << 2) + rg;
      float cv = ctxa[nf][rg] / lsum[rg];
      u32 ch, cl;
      splitbf(cv, ch, cl);
      size_t co = (size_t)(b * kS + query) * (kH * kDH) + hh * kDH + d;
      ctxH[co] = (u16)ch;
      ctxL[co] = (u16)cl;
    }
  }
}

// ---------------- silu(gu.g)*gu.u with fused split (fused-GU input) ----------
__global__ __launch_bounds__(256) void silu_mul_split_kernel(
    const float* __restrict__ gu, u16* __restrict__ hi, u16* __restrict__ lo,
    int keepR) {
  int i = blockIdx.x * 256 + threadIdx.x;
  int total = keepR * (kFI / 4);
  if (i >= total) return;
  int row = i / (kFI / 4);
  int c4 = (i - row * (kFI / 4)) * 4;
  float4 gv = *(const float4*)&gu[(size_t)row * kGU + c4];
  float4 uv = *(const float4*)&gu[(size_t)row * kGU + kFI + c4];
  float m0 = (gv.x / (1.f + expf(-gv.x))) * uv.x;
  float m1 = (gv.y / (1.f + expf(-gv.y))) * uv.y;
  float m2 = (gv.z / (1.f + expf(-gv.z))) * uv.z;
  float m3 = (gv.w / (1.f + expf(-gv.w))) * uv.w;
  u32 h0, h1, h2, h3, l0, l1, l2, l3;
  splitbf(m0, h0, l0); splitbf(m1, h1, l1);
  splitbf(m2, h2, l2); splitbf(m3, h3, l3);
  uint2 ph, pl;
  ph.x = h0 | (h1 << 16); ph.y = h2 | (h3 << 16);
  pl.x = l0 | (l1 << 16); pl.y = l2 | (l3 << 16);
  *(uint2*)&hi[(size_t)row * kFI + c4] = ph;
  *(uint2*)&lo[(size_t)row * kFI + c4] = pl;
}

// ---------------- weight transpose + split with dst stride/offset ------------
__global__ __launch_bounds__(256) void tsplit_kernel(const float* __restrict__ W,
    u16* __restrict__ Th, u16* __restrict__ Tl, int N, int K, size_t dstStride) {
  size_t mat = (size_t)blockIdx.z * (size_t)K * N;
  size_t dob = (size_t)blockIdx.z * dstStride;
  int n0 = blockIdx.x * 64, k0 = blockIdx.y * 64;
  __shared__ float T[64][65];
  int t = threadIdx.x;
#pragma unroll
  for (int p = 0; p < 16; ++p) {
    int idx = t + p * 256;
    int kl = idx >> 6, nl = idx & 63;
    T[nl][kl] = W[mat + (size_t)(k0 + kl) * N + n0 + nl];
  }
  __syncthreads();
  int nl = t >> 2, kg = t & 3;
  size_t ob = dob + (size_t)(n0 + nl) * K + k0 + kg * 16;
#pragma unroll
  for (int i = 0; i < 4; ++i) {
    int kk = kg * 16 + i * 4;
    u32 h0, h1, h2, h3, l0, l1, l2, l3;
    splitbf(T[nl][kk + 0], h0, l0); splitbf(T[nl][kk + 1], h1, l1);
    splitbf(T[nl][kk + 2], h2, l2); splitbf(T[nl][kk + 3], h3, l3);
    uint2 ph, pl;
    ph.x = h0 | (h1 << 16); ph.y = h2 | (h3 << 16);
    pl.x = l0 | (l1 << 16); pl.y = l2 | (l3 << 16);
    *(uint2*)&Th[ob + i * 4] = ph;
    *(uint2*)&Tl[ob + i * 4] = pl;
  }
}

// ---------------- weight transpose, hi only: W[K][N] -> Bt bf16 [N][K] -------
__global__ __launch_bounds__(256) void tconv_kernel(const float* __restrict__ W,
    u16* __restrict__ Bt, int N, int K) {
  int n0 = blockIdx.x * 64, k0 = blockIdx.y * 64;
  __shared__ float T[64][65];
  int t = threadIdx.x;
#pragma unroll
  for (int p = 0; p < 16; ++p) {
    int idx = t + p * 256;
    int kl = idx >> 6, nl = idx & 63;
    T[nl][kl] = W[(size_t)(k0 + kl) * N + n0 + nl];
  }
  __syncthreads();
  int nl = t >> 2, kg = t & 3;
  size_t ob = (size_t)(n0 + nl) * K + k0 + kg * 16;
#pragma unroll
  for (int i = 0; i < 4; ++i) {
    int kk = kg * 16 + i * 4;
    uint2 ph;
    ph.x = f2bf1(T[nl][kk + 0]) | (f2bf1(T[nl][kk + 1]) << 16);
    ph.y = f2bf1(T[nl][kk + 2]) | (f2bf1(T[nl][kk + 3]) << 16);
    *(uint2*)&Bt[ob + i * 4] = ph;
  }
}

// ---------------- bf16x3 MFMA GEMM (global_load_lds staging) -----------------
// MODE 0: C=A@B   1: C=A@B+Add   2: masked rows   3: COMPACT scatter
template <int MODE>
__global__ __launch_bounds__(256) void gemm_bf3(
    const u16* __restrict__ Ah, const u16* __restrict__ Al,
    const u16* __restrict__ Bh, const u16* __restrict__ Bl,
    float* __restrict__ C, int N, int K,
    const float* __restrict__ Add, const int* __restrict__ mask, int gridR,
    int keepM) {
  __shared__ __align__(16) char AsH[16384];
  __shared__ __align__(16) char AsL[16384];
  __shared__ __align__(16) char BsH[16384];
  __shared__ __align__(16) char BsL[16384];
  int t = threadIdx.x;
  int lane = t & 63, w = t >> 6;
  int wr = w >> 1, wc = w & 1;
  int lid = xcd_remap((int)blockIdx.x, (int)gridDim.x);
  int row0 = (lid % gridR) * 128, col0 = (lid / gridR) * 128;
  f32x4 acc[4][4];
#pragma unroll
  for (int i = 0; i < 4; ++i)
#pragma unroll
    for (int j = 0; j < 4; ++j) acc[i][j] = {0.f, 0.f, 0.f, 0.f};

  for (int k0 = 0; k0 < K; k0 += 64) {
    stage_lds16(Ah, K, row0, k0, AsH, t);
    stage_lds16(Al, K, row0, k0, AsL, t);
    stage_lds16(Bh, K, col0, k0, BsH, t);
    stage_lds16(Bl, K, col0, k0, BsL, t);
    __syncthreads();
#pragma unroll
    for (int ks = 0; ks < 2; ++ks) {
      bf16x8 ah[4], al4[4], bh[4], bl4[4];
      int kb = ks * 64 + ((lane >> 4) << 4);
#pragma unroll
      for (int i = 0; i < 4; ++i) {
        int m = wr * 64 + i * 16 + (lane & 15);
        int n = wc * 64 + i * 16 + (lane & 15);
        int ao = m * 128 + (kb ^ ((m & 7) << 4));
        int bo = n * 128 + (kb ^ ((n & 7) << 4));
        ah[i] = *(bf16x8*)(AsH + ao);
        al4[i] = *(bf16x8*)(AsL + ao);
        bh[i] = *(bf16x8*)(BsH + bo);
        bl4[i] = *(bf16x8*)(BsL + bo);
      }
#pragma unroll
      for (int mb = 0; mb < 4; ++mb)
#pragma unroll
        for (int nb = 0; nb < 4; ++nb) {
          acc[mb][nb] = __builtin_amdgcn_mfma_f32_16x16x32_bf16(
              ah[mb], bh[nb], acc[mb][nb], 0, 0, 0);
          acc[mb][nb] = __builtin_amdgcn_mfma_f32_16x16x32_bf16(
              ah[mb], bl4[nb], acc[mb][nb], 0, 0, 0);
          acc[mb][nb] = __builtin_amdgcn_mfma_f32_16x16x32_bf16(
              al4[mb], bh[nb], acc[mb][nb], 0, 0, 0);
        }
    }
    __syncthreads();
  }
#pragma unroll
  for (int mb = 0; mb < 4; ++mb) {
    int rb = row0 + wr * 64 + mb * 16 + ((lane >> 4) << 2);
#pragma unroll
    for (int rg = 0; rg < 4; ++rg) {
      int r = rb + rg;
      if (MODE == 2 && !mask[r]) continue;
      if (MODE == 3 && r >= keepM) continue;
      int ro = (MODE == 3) ? mask[r] : r;   // MODE 3: mask ptr holds cidx
#pragma unroll
      for (int nb = 0; nb < 4; ++nb) {
        int c = col0 + wc * 64 + nb * 16 + (lane & 15);
        float vv = acc[mb][nb][rg];
        if (MODE >= 1) vv += Add[(size_t)ro * N + c];
        C[(size_t)ro * N + c] = vv;
      }
    }
  }
}

// ---------------- lm_head fast: gload_lds staging + A-supertile ordering -----
__global__ __launch_bounds__(256) void lmhead_fast(const u16* __restrict__ Abf,
    const u16* __restrict__ Bt, float* __restrict__ C, int N, int K, int gridR) {
  __shared__ __align__(16) char AsB[16384];
  __shared__ __align__(16) char BsB[16384];
  int t = threadIdx.x;
  int lane = t & 63, w = t >> 6;
  int wr = w >> 1, wc = w & 1;
  int lid = xcd_remap((int)blockIdx.x, (int)gridDim.x);
  int panels = (int)gridDim.x / gridR;
  const int RG = 14;
  int fullg = gridR / RG;
  int lastr = gridR - fullg * RG;
  int fgb = fullg * RG * panels;
  int row, panel;
  if (lid < fgb) {
    int g = lid / (RG * panels);
    int r2 = lid % (RG * panels);
    row = g * RG + (r2 % RG);
    panel = r2 / RG;
  } else {
    int r2 = lid - fgb;
    row = fullg * RG + (r2 % lastr);
    panel = r2 / lastr;
  }
  int row0 = row * 128, col0 = panel * 128;
  f32x4 acc[4][4];
#pragma unroll
  for (int i = 0; i < 4; ++i)
#pragma unroll
    for (int j = 0; j < 4; ++j) acc[i][j] = {0.f, 0.f, 0.f, 0.f};

  for (int k0 = 0; k0 < K; k0 += 64) {
    stage_lds16(Abf, K, row0, k0, AsB, t);
    stage_lds16(Bt, K, col0, k0, BsB, t);
    __syncthreads();
#pragma unroll
    for (int ks = 0; ks < 2; ++ks) {
      bf16x8 af[4], bfr[4];
      int kb = ks * 64 + ((lane >> 4) << 4);
#pragma unroll
      for (int i = 0; i < 4; ++i) {
        int m = wr * 64 + i * 16 + (lane & 15);
        int n = wc * 64 + i * 16 + (lane & 15);
        af[i] = *(bf16x8*)(AsB + m * 128 + (kb ^ ((m & 7) << 4)));
        bfr[i] = *(bf16x8*)(BsB + n * 128 + (kb ^ ((n & 7) << 4)));
      }
#pragma unroll
      for (int mb = 0; mb < 4; ++mb)
#pragma unroll
        for (int nb = 0; nb < 4; ++nb)
          acc[mb][nb] = __builtin_amdgcn_mfma_f32_16x16x32_bf16(
              af[mb], bfr[nb], acc[mb][nb], 0, 0, 0);
    }
    __syncthreads();
  }
#pragma unroll
  for (int mb = 0; mb < 4; ++mb) {
    int row2 = row0 + wr * 64 + mb * 16 + ((lane >> 4) << 2);
#pragma unroll
    for (int nb = 0; nb < 4; ++nb) {
      int col = col0 + wc * 64 + nb * 16 + (lane & 15);
#pragma unroll
      for (int rg = 0; rg < 4; ++rg)
        __builtin_nontemporal_store(acc[mb][nb][rg],
                                    &C[(size_t)(row2 + rg) * N + col]);
    }
  }
}

// ---------------- lm_head hybrid tail: A bf16 (ws) x B f32 via coalesced LDS -
__global__ __launch_bounds__(256) void lmhead_hyb(const u16* __restrict__ Abf2,
    const float* __restrict__ Bm, float* __restrict__ C, int N, int K, int gridR) {
  __shared__ __align__(16) char AsB[16384];
  __shared__ __align__(16) char BsB[16384];
  __shared__ float sBf[64][132];
  int t = threadIdx.x;
  int lane = t & 63, w = t >> 6;
  int wr = w >> 1, wc = w & 1;
  int lid = xcd_remap((int)blockIdx.x, (int)gridDim.x);
  int row0 = (lid % gridR) * 128, col0 = (lid / gridR) * 128;
  f32x4 acc[4][4];
#pragma unroll
  for (int i = 0; i < 4; ++i)
#pragma unroll
    for (int j = 0; j < 4; ++j) acc[i][j] = {0.f, 0.f, 0.f, 0.f};

  for (int k0 = 0; k0 < K; k0 += 64) {
    stage_lds16(Abf2, K, row0, k0, AsB, t);
#pragma unroll
    for (int p = 0; p < 8; ++p) {
      int idx = t + p * 256;
      int kk = idx >> 5, c4 = (idx & 31) << 2;
      *(float4*)&sBf[kk][c4] = *(const float4*)&Bm[(size_t)(k0 + kk) * N + col0 + c4];
    }
    __syncthreads();
#pragma unroll
    for (int p = 0; p < 4; ++p) {
      int nl = t & 127;
      int kb = ((t >> 7) << 3) + p * 16;
      unsigned pk[4];
#pragma unroll
      for (int j = 0; j < 4; ++j)
        pk[j] = f2bf1(sBf[kb + 2 * j][nl]) | (f2bf1(sBf[kb + 2 * j + 1][nl]) << 16);
      uint4 w4; w4.x = pk[0]; w4.y = pk[1]; w4.z = pk[2]; w4.w = pk[3];
      *(uint4*)(BsB + nl * 128 + ((kb * 2) ^ ((nl & 7) << 4))) = w4;
    }
    __syncthreads();
#pragma unroll
    for (int ks = 0; ks < 2; ++ks) {
      bf16x8 af[4], bfr[4];
      int kb = ks * 64 + ((lane >> 4) << 4);
#pragma unroll
      for (int i = 0; i < 4; ++i) {
        int m = wr * 64 + i * 16 + (lane & 15);
        int n = wc * 64 + i * 16 + (lane & 15);
        af[i] = *(bf16x8*)(AsB + m * 128 + (kb ^ ((m & 7) << 4)));
        bfr[i] = *(bf16x8*)(BsB + n * 128 + (kb ^ ((n & 7) << 4)));
      }
#pragma unroll
      for (int mb = 0; mb < 4; ++mb)
#pragma unroll
        for (int nb = 0; nb < 4; ++nb)
          acc[mb][nb] = __builtin_amdgcn_mfma_f32_16x16x32_bf16(
              af[mb], bfr[nb], acc[mb][nb], 0, 0, 0);
    }
    __syncthreads();
  }
#pragma unroll
  for (int mb = 0; mb < 4; ++mb) {
    int row = row0 + wr * 64 + mb * 16 + ((lane >> 4) << 2);
#pragma unroll
    for (int nb = 0; nb < 4; ++nb) {
      int col = col0 + wc * 64 + nb * 16 + (lane & 15);
#pragma unroll
      for (int rg = 0; rg < 4; ++rg)
        __builtin_nontemporal_store(acc[mb][nb][rg],
                                    &C[(size_t)(row + rg) * N + col]);
    }
  }
}

__global__ __launch_bounds__(256) void copy_kernel(const float* __restrict__ src,
    float* __restrict__ dst, int n) {
  int i = blockIdx.x * 256 + threadIdx.x;
  if (i < n) dst[i] = src[i];
}

__global__ void finish_kernel(const float* __restrict__ aux, float* __restrict__ dst) {
  dst[0] = aux[0];
}

// ---------------- orchestration ---------------------------------------------
extern "C" void kernel_launch(void* const* d_in, const int* in_sizes, int n_in,
                              void* d_out, int out_size, void* d_ws, size_t ws_size,
                              hipStream_t stream) {
  const int* ids = (const int*)d_in[0];
  const float* emb = (const float*)d_in[1];
  const float* Wq = (const float*)d_in[2];
  const float* Wk = (const float*)d_in[3];
  const float* Wv = (const float*)d_in[4];
  const float* Wo = (const float*)d_in[5];
  const float* Wg = (const float*)d_in[6];
  const float* Wu = (const float*)d_in[7];
  const float* Wd = (const float*)d_in[8];
  const float* n1 = (const float*)d_in[9];
  const float* n2 = (const float*)d_in[10];
  const float* rw = (const float*)d_in[11];
  const float* fn = (const float*)d_in[12];
  const float* lmh = (const float*)d_in[13];
  float* out = (float*)d_out;

  // --- d_ws (~1.82 MiB) ---
  float* ws = (float*)d_ws;
  size_t woff = 0;
  float* cosT = ws + woff;   woff += (size_t)kS * 32;
  float* sinT = ws + woff;   woff += (size_t)kS * 32;
  float* scores = ws + woff; woff += kT;
  float* aux = ws + woff;    woff += 4;
  int* mask = (int*)(ws + woff); woff += kT;
  int* cidx = (int*)(ws + woff); woff += kT;
  u16* Abf2 = (u16*)(ws + woff);  // (kT-kR1)*kD u16

  // --- d_out layout: front scratch | x | Abf | Bt (tail) ---
  float* x = out + kXOff;
  u16* Abf = (u16*)(out + kAbfOff);
  u16* Bt = (u16*)(out + kBtOff);
  size_t off = 0;
  auto alloc = [&](size_t n) { float* p = out + off; off += n; return p; };
  float* qkv  = alloc((size_t)kT * kQKV);     // fused q|k|v f32
  float* xa   = alloc((size_t)kT * kD);
  float* gu   = alloc((size_t)kT * kGU);      // fused g|u f32
  u16* hH   = (u16*)alloc((size_t)kT * kD / 2);
  u16* hL   = (u16*)alloc((size_t)kT * kD / 2);
  u16* ctxH = (u16*)alloc((size_t)kT * kD / 2);
  u16* ctxL = (u16*)alloc((size_t)kT * kD / 2);
  u16* mmH  = (u16*)alloc((size_t)kT * kFI / 2);
  u16* mmL  = (u16*)alloc((size_t)kT * kFI / 2);
  u16* QhB  = (u16*)alloc((size_t)kT * kH * kDH / 2);
  u16* QlB  = (u16*)alloc((size_t)kT * kH * kDH / 2);
  u16* KhB  = (u16*)alloc((size_t)kT * kKV * kDH / 2);
  u16* KlB  = (u16*)alloc((size_t)kT * kKV * kDH / 2);
  u16* VTh  = (u16*)alloc((size_t)kT * kKV * kDH / 2);
  u16* VTl  = (u16*)alloc((size_t)kT * kKV * kDH / 2);
  u16* WqkvH = (u16*)alloc(1572864); u16* WqkvL = (u16*)alloc(1572864);
  u16* WoH   = (u16*)alloc(1048576); u16* WoL   = (u16*)alloc(1048576);
  u16* WguH  = (u16*)alloc(5767168); u16* WguL  = (u16*)alloc(5767168);
  u16* WdH   = (u16*)alloc(2883584); u16* WdL   = (u16*)alloc(2883584);
  (void)in_sizes; (void)n_in; (void)ws_size;

  tables_kernel<<<kS * 32 / 256, 256, 0, stream>>>(cosT, sinT);
  init_kernel<<<1, 256, 0, stream>>>(mask, aux);
  embed_kernel<<<kT, 256, 0, stream>>>(ids, emb, x);

  // weight transpose-splits into FUSED buffers (per-blk dst strides)
  const size_t sQKV = (size_t)kQKV * kD;
  const size_t sGU = (size_t)kGU * kD;
  tsplit_kernel<<<dim3(16, 16, 2), 256, 0, stream>>>(
      Wq, WqkvH, WqkvL, 1024, 1024, sQKV);
  tsplit_kernel<<<dim3(4, 16, 2), 256, 0, stream>>>(
      Wk, WqkvH + 1024 * 1024, WqkvL + 1024 * 1024, 256, 1024, sQKV);
  tsplit_kernel<<<dim3(4, 16, 2), 256, 0, stream>>>(
      Wv, WqkvH + 1280 * 1024, WqkvL + 1280 * 1024, 256, 1024, sQKV);
  tsplit_kernel<<<dim3(16, 16, 2), 256, 0, stream>>>(
      Wo, WoH, WoL, 1024, 1024, (size_t)1024 * 1024);
  tsplit_kernel<<<dim3(44, 16, 2), 256, 0, stream>>>(
      Wg, WguH, WguL, 2816, 1024, sGU);
  tsplit_kernel<<<dim3(44, 16, 2), 256, 0, stream>>>(
      Wu, WguH + 2816 * 1024, WguL + 2816 * 1024, 2816, 1024, sGU);
  tsplit_kernel<<<dim3(16, 44, 2), 256, 0, stream>>>(
      Wd, WdH, WdL, 1024, 2816, (size_t)2816 * 1024);
  tconv_kernel<<<dim3(kV / 64, kD / 64), 256, 0, stream>>>(lmh, Bt, kV, kD);

  const int keeps[3] = {2744, 1838, 1231};  // int(n*0.67) chain from 4096
  const int tiles[3] = {22, 15, 10};        // ceil(keep/128)
  for (int step = 0; step < 3; ++step) {
    int blk = step % 2;
    int keep = keeps[step], nt = tiles[step], keepR = nt * 128;
    size_t qkvo = (size_t)blk * sQKV;
    size_t oo = (size_t)blk * (kH * kDH) * kD;
    size_t guo = (size_t)blk * sGU;
    size_t dofs = (size_t)blk * kFI * kD;
    router_kernel<<<kT, 64, 0, stream>>>(x, rw, scores);
    topk_kernel<<<1, 1024, 0, stream>>>(scores, mask, aux, keep);
    scan_kernel<<<1, 1024, 0, stream>>>(mask, cidx, keep, keepR);
    rmsnorm_split_kernel<<<kT, 256, 0, stream>>>(x, n1 + (size_t)blk * kD, hH, hL);
    gemm_bf3<0><<<32 * 12, 256, 0, stream>>>(
        hH, hL, WqkvH + qkvo, WqkvL + qkvo, qkv, kQKV, kD, nullptr, nullptr, 32, 0);
    rope_split_kernel<<<(kT * kH * 32 + kT * kKV * 32) / 256, 256, 0, stream>>>(
        qkv, cosT, sinT, QhB, QlB, KhB, KlB);
    vtsplit_kernel<<<dim3(kS / 64, kKV, kB), 256, 0, stream>>>(qkv, VTh, VTl);
    attn_mfma<<<dim3(kS / 64, kH, kB), 256, 0, stream>>>(
        QhB, QlB, KhB, KlB, VTh, VTl, ctxH, ctxL);
    gemm_bf3<1><<<32 * 8, 256, 0, stream>>>(
        ctxH, ctxL, WoH + oo, WoL + oo, xa, kD, kH * kDH, x, nullptr, 32, 0);
    rmsnorm_split_gather<<<keepR, 256, 0, stream>>>(
        xa, n2 + (size_t)blk * kD, cidx, hH, hL);
    gemm_bf3<0><<<nt * 44, 256, 0, stream>>>(
        hH, hL, WguH + guo, WguL + guo, gu, kGU, kD, nullptr, nullptr, nt, 0);
    silu_mul_split_kernel<<<(keepR * (kFI / 4) + 255) / 256, 256, 0, stream>>>(
        gu, mmH, mmL, keepR);
    gemm_bf3<3><<<nt * 8, 256, 0, stream>>>(
        mmH, mmL, WdH + dofs, WdL + dofs, x, kD, kFI, xa, cidx, nt, keep);
  }

  // lm_head
  finalnorm_conv<<<kT, 256, 0, stream>>>(x, fn, Abf);
  copy_kernel<<<(kT - kR1) * kD / 2 / 256, 256, 0, stream>>>(
      (const float*)(Abf + (size_t)kR1 * kD), (float*)Abf2, (kT - kR1) * kD / 2);
  lmhead_fast<<<(kR1 / 128) * (kV / 128), 256, 0, stream>>>(
      Abf, Bt, out, kV, kD, kR1 / 128);
  lmhead_hyb<<<((kT - kR1) / 128) * (kV / 128), 256, 0, stream>>>(
      Abf2, lmh, out + (size_t)kR1 * kV, kV, kD, (kT - kR1) / 128);
  finish_kernel<<<1, 1, 0, stream>>>(aux, out + (size_t)out_size - 1);
}

// Round 19
// 2042.113 us; speedup vs baseline: 11.2268x; 1.1156x over previous
//
#include <hip/hip_runtime.h>
#include <cmath>

// MoR forward, round 19 = round 18 (passing, 2.28 ms) + Q-SIDE COMPACTION:
// reference only consumes block output at masked tokens -> attention queries,
// ctx, Wo, and the whole post-attention chain only matter for ACTIVE tokens
// (K/V stay full: inactive tokens are still keys). scan2 builds a per-batch
// padded compact list (batch-uniform 64-query attention blocks; fixed grids
// keepR2={2944,2048,1408}); attn gathers Q via sTok and writes compact ctx;
// Wo = gemm_bf3<4> (gathered residual); Wd scatters via cidx2. Padding rows
// duplicate real active tokens -> duplicate writes carry identical values.
// Active-token numerics bit-identical to round 18.

constexpr int kB = 2, kS = 2048, kD = 1024, kH = 16, kKV = 4, kDH = 64,
              kFI = 2816, kV = 32000, kT = kB * kS;
constexpr size_t kBtOff  = 114688000;
constexpr size_t kAbfOff = 112590848;
constexpr size_t kXOff   = 108396544;
constexpr int kR1 = 3456;
constexpr int kQKV = 1536;               // 1024 q | 256 k | 256 v
constexpr int kGU = 5632;                // 2816 g | 2816 u

typedef __attribute__((ext_vector_type(8))) __bf16 bf16x8;
typedef __attribute__((ext_vector_type(4))) float f32x4;
typedef unsigned short u16;
typedef unsigned int u32;

__device__ inline u32 f2bf1(float f) {   // RTN-even bf16, low 16 bits
  u32 u = __builtin_bit_cast(u32, f);
  return (u + 0x7FFFu + ((u >> 16) & 1u)) >> 16;
}
__device__ inline void splitbf(float v, u32& h, u32& l) {
  h = f2bf1(v);
  float hf = __builtin_bit_cast(float, h << 16);
  l = f2bf1(v - hf);                     // v-hf exact (Sterbenz)
}
__device__ inline int xcd_remap(int hb, int nwg) {
  int q = nwg >> 3, r = nwg & 7;
  int xcd = hb & 7, pos = hb >> 3;
  int start = (xcd < r) ? xcd * (q + 1) : r * (q + 1) + (xcd - r) * q;
  return start + pos;
}

// Stage one 16KB [128 rows x 64k bf16] tile via global_load_lds: linear dest +
// inverse-swizzled per-lane global source (bit-identical LDS image; r18-proven).
__device__ inline void stage_lds16(const u16* __restrict__ gbase, int K,
                                   int row0, int k0, char* ldsbase, int t) {
  int w = t >> 6, lane = t & 63;
#pragma unroll
  for (int i = 0; i < 4; ++i) {
    int wb = (w * 4 + i) * 1024;
    int L = wb + lane * 16;
    int r = L >> 7, inner = L & 127;
    int kc0 = (inner ^ ((r & 7) << 4)) >> 3;
    const u16* g = gbase + (size_t)(row0 + r) * K + k0 + kc0 * 4;
    __builtin_amdgcn_global_load_lds(
        (const __attribute__((address_space(1))) u32*)g,
        (__attribute__((address_space(3))) u32*)(ldsbase + wb), 16, 0, 0);
  }
}

// ---------------- RoPE tables -----------------------------------------------
__global__ __launch_bounds__(256) void tables_kernel(float* __restrict__ cosT,
                                                     float* __restrict__ sinT) {
  int tid = blockIdx.x * 256 + threadIdx.x;
  int t = tid >> 5, d = tid & 31;
  float inv = (float)pow(10000.0, -(double)d / 32.0);
  float fr = (float)t * inv;
  cosT[tid] = (float)cos((double)fr);
  sinT[tid] = (float)sin((double)fr);
}

__global__ void init_kernel(int* __restrict__ mask, float* __restrict__ aux) {
  int t = threadIdx.x;
  for (int e = t; e < kT; e += 256) mask[e] = 1;
  if (t == 0) aux[0] = 0.f;
}

__global__ __launch_bounds__(256) void embed_kernel(const int* __restrict__ ids,
    const float* __restrict__ emb, float* __restrict__ x) {
  int tid = blockIdx.x * 256 + threadIdx.x;
  int token = tid >> 8;
  int c4 = (tid & 255) << 2;
  int id = ids[token];
  *(float4*)&x[(size_t)token * kD + c4] =
      *(const float4*)&emb[(size_t)id * kD + c4];
}

// ---------------- per-batch padded compact list (LDS-built) ------------------
// cidx2[0..keepR2): batch0 actives padded to 64-mult with its last active,
// then batch1 likewise, tail padded with overall last. Ascending per segment.
__global__ __launch_bounds__(1024) void scan2_kernel(const int* __restrict__ mask,
    int* __restrict__ cidx2, int keepR2) {
  __shared__ int sv[1024];
  __shared__ int slist[2944];            // >= max keepR2
  __shared__ int padlen_s;
  int t = threadIdx.x;
  if (t == 0) padlen_s = 0;
  __syncthreads();
  for (int b = 0; b < 2; ++b) {
    int base = b * 2048;
    int m0 = mask[base + t * 2], m1 = mask[base + t * 2 + 1];
    sv[t] = m0 + m1;
    __syncthreads();
    for (int off = 1; off < 1024; off <<= 1) {
      int v = (t >= off) ? sv[t - off] : 0;
      __syncthreads();
      sv[t] += v;
      __syncthreads();
    }
    int pre = (t == 0) ? 0 : sv[t - 1];
    int cb = sv[1023];
    int seg = padlen_s;                  // uniform; settled by prior barrier
    if (m0) slist[seg + pre] = base + t * 2;
    if (m1) slist[seg + pre + m0] = base + t * 2 + 1;
    __syncthreads();
    int padded = ((cb + 63) >> 6) << 6;
    if (cb > 0) {
      int last = slist[seg + cb - 1];
      for (int e = cb + t; e < padded; e += 1024) slist[seg + e] = last;
    }
    __syncthreads();
    if (t == 0) padlen_s = seg + padded;
    __syncthreads();
  }
  int pl = padlen_s;
  int lastAll = slist[pl - 1];
  for (int e = pl + t; e < keepR2; e += 1024) slist[e] = lastAll;
  __syncthreads();
  for (int e = t; e < keepR2; e += 1024) cidx2[e] = slist[e];
}

// ---------------- RMSNorm with fused hi/lo split (contiguous rows) -----------
__global__ __launch_bounds__(256) void rmsnorm_split_kernel(
    const float* __restrict__ x, const float* __restrict__ w,
    u16* __restrict__ ohi, u16* __restrict__ olo) {
  int tok = blockIdx.x, t = threadIdx.x;
  const float* xr = x + (size_t)tok * kD;
  float4 xv = *(const float4*)&xr[t * 4];
  float s = xv.x * xv.x + xv.y * xv.y + xv.z * xv.z + xv.w * xv.w;
#pragma unroll
  for (int off = 1; off < 64; off <<= 1) s += __shfl_xor(s, off);
  __shared__ float red[4];
  if ((t & 63) == 0) red[t >> 6] = s;
  __syncthreads();
  float tot = red[0] + red[1] + red[2] + red[3];
  float sc = 1.f / sqrtf(tot * (1.f / kD) + 1e-6f);
  float4 wv = *(const float4*)&w[t * 4];
  float o0 = xv.x * sc * wv.x, o1 = xv.y * sc * wv.y;
  float o2 = xv.z * sc * wv.z, o3 = xv.w * sc * wv.w;
  u32 h0, h1, h2, h3, l0, l1, l2, l3;
  splitbf(o0, h0, l0); splitbf(o1, h1, l1);
  splitbf(o2, h2, l2); splitbf(o3, h3, l3);
  uint2 ph, pl;
  ph.x = h0 | (h1 << 16); ph.y = h2 | (h3 << 16);
  pl.x = l0 | (l1 << 16); pl.y = l2 | (l3 << 16);
  *(uint2*)&ohi[(size_t)tok * kD + t * 4] = ph;
  *(uint2*)&olo[(size_t)tok * kD + t * 4] = pl;
}

// ---------------- final rmsnorm + fn scale -> bf16 A for lm_head -------------
__global__ __launch_bounds__(256) void finalnorm_conv(const float* __restrict__ x,
    const float* __restrict__ fnw, u16* __restrict__ Abf) {
  int tok = blockIdx.x, t = threadIdx.x;
  const float* xr = x + (size_t)tok * kD;
  float4 xv = *(const float4*)&xr[t * 4];
  float s = xv.x * xv.x + xv.y * xv.y + xv.z * xv.z + xv.w * xv.w;
#pragma unroll
  for (int off = 1; off < 64; off <<= 1) s += __shfl_xor(s, off);
  __shared__ float red[4];
  if ((t & 63) == 0) red[t >> 6] = s;
  __syncthreads();
  float tot = red[0] + red[1] + red[2] + red[3];
  float sc = 1.f / sqrtf(tot * (1.f / kD) + 1e-6f);
  float4 wv = *(const float4*)&fnw[t * 4];
  uint2 ph;
  ph.x = f2bf1(xv.x * sc * wv.x) | (f2bf1(xv.y * sc * wv.y) << 16);
  ph.y = f2bf1(xv.z * sc * wv.z) | (f2bf1(xv.w * sc * wv.w) << 16);
  *(uint2*)&Abf[(size_t)tok * kD + t * 4] = ph;
}

// ---------------- router (f64 accumulate) ------------------------------------
__global__ __launch_bounds__(64) void router_kernel(const float* __restrict__ x,
    const float* __restrict__ rw, float* __restrict__ scores) {
  int tok = blockIdx.x, lane = threadIdx.x;
  const float* xr = x + (size_t)tok * kD;
  double s = 0.0;
#pragma unroll
  for (int e = 0; e < kD / 64; ++e)
    s += (double)xr[lane + e * 64] * (double)rw[lane + e * 64];
#pragma unroll
  for (int off = 1; off < 64; off <<= 1) s += __shfl_xor(s, off);
  if (lane == 0) {
    float z = (float)s;
    scores[tok] = 1.f / (1.f + expf(-z));
  }
}

// ---------------- exact top-k (bitonic, ties -> lower index) -----------------
__global__ __launch_bounds__(1024) void topk_kernel(const float* __restrict__ scores,
    int* __restrict__ mask, float* __restrict__ aux, int keep) {
  __shared__ float sv[kT];
  __shared__ int si[kT];
  __shared__ float red[16];
  int t = threadIdx.x;
  for (int e = t; e < kT; e += 1024) {
    sv[e] = mask[e] ? scores[e] : -INFINITY;
    si[e] = e;
  }
  __syncthreads();
  for (int k = 2; k <= kT; k <<= 1) {
    for (int j = k >> 1; j > 0; j >>= 1) {
      for (int e = t; e < kT; e += 1024) {
        int p = e ^ j;
        if (p > e) {
          float v1 = sv[e], v2 = sv[p];
          int i1 = si[e], i2 = si[p];
          bool before = (v1 > v2) || (v1 == v2 && i1 < i2);
          bool desc = ((e & k) == 0);
          if (desc ? !before : before) {
            sv[e] = v2; sv[p] = v1; si[e] = i2; si[p] = i1;
          }
        }
      }
      __syncthreads();
    }
  }
  for (int e = t; e < kT; e += 1024) mask[si[e]] = (e < keep) ? 1 : 0;
  float ps = 0.f;
  for (int e = t; e < keep; e += 1024) ps += sv[e];
#pragma unroll
  for (int off = 1; off < 64; off <<= 1) ps += __shfl_xor(ps, off);
  if ((t & 63) == 0) red[t >> 6] = ps;
  __syncthreads();
  if (t == 0) {
    float tot = 0.f;
    for (int i = 0; i < 16; ++i) tot += red[i];
    aux[0] += -(tot / (float)keep) * 1e-3f;
  }
}

// ---------------- RoPE with fused bf16 hi/lo split, fused-QKV input ----------
__global__ __launch_bounds__(256) void rope_split_kernel(
    const float* __restrict__ qkv,
    const float* __restrict__ cosT, const float* __restrict__ sinT,
    u16* __restrict__ Qh, u16* __restrict__ Ql,
    u16* __restrict__ Kh, u16* __restrict__ Kl) {
  int tid = blockIdx.x * 256 + threadIdx.x;
  const int QP = kT * kH * 32;
  const float* base;
  u16 *oh, *ol;
  size_t outoff;
  int token, d;
  if (tid < QP) {
    token = tid >> 9;
    int r = tid & 511;
    int hh = r >> 5; d = r & 31;
    base = qkv + (size_t)token * kQKV + hh * kDH;
    outoff = (size_t)token * (kH * kDH) + hh * kDH;
    oh = Qh; ol = Ql;
  } else {
    int p = tid - QP;
    token = p >> 7;
    int r = p & 127;
    int hh = r >> 5; d = r & 31;
    base = qkv + (size_t)token * kQKV + 1024 + hh * kDH;
    outoff = (size_t)token * (kKV * kDH) + hh * kDH;
    oh = Kh; ol = Kl;
  }
  int s = token & (kS - 1);
  float c = cosT[s * 32 + d], sn = sinT[s * 32 + d];
  float x1 = base[d], x2 = base[d + 32];
  float v1 = x1 * c - x2 * sn;
  float v2 = x2 * c + x1 * sn;
  u32 h1, l1, h2, l2;
  splitbf(v1, h1, l1);
  splitbf(v2, h2, l2);
  oh[outoff + d] = (u16)h1;      ol[outoff + d] = (u16)l1;
  oh[outoff + d + 32] = (u16)h2; ol[outoff + d + 32] = (u16)l2;
}

// ---------------- V transpose-split from fused qkv (v at col 1280) -----------
__global__ __launch_bounds__(256) void vtsplit_kernel(const float* __restrict__ qkv,
    u16* __restrict__ Th, u16* __restrict__ Tl) {
  int ktile = blockIdx.x, kv = blockIdx.y, b = blockIdx.z;
  __shared__ float T[64][65];
  int t = threadIdx.x;
#pragma unroll
  for (int p = 0; p < 16; ++p) {
    int idx = t + p * 256;
    int key = idx >> 6, d = idx & 63;
    T[key][d] =
        qkv[(size_t)(b * kS + ktile * 64 + key) * kQKV + 1280 + kv * kDH + d];
  }
  __syncthreads();
  int dr = t >> 2, kg = t & 3;
  size_t ob = ((size_t)(b * kKV + kv) * kDH + dr) * kS + ktile * 64 + kg * 16;
#pragma unroll
  for (int i = 0; i < 4; ++i) {
    int kk = kg * 16 + i * 4;
    u32 h0, h1, h2, h3, l0, l1, l2, l3;
    splitbf(T[kk + 0][dr], h0, l0); splitbf(T[kk + 1][dr], h1, l1);
    splitbf(T[kk + 2][dr], h2, l2); splitbf(T[kk + 3][dr], h3, l3);
    uint2 ph, pl;
    ph.x = h0 | (h1 << 16); ph.y = h2 | (h3 << 16);
    pl.x = l0 | (l1 << 16); pl.y = l2 | (l3 << 16);
    *(uint2*)&Th[ob + i * 4] = ph;
    *(uint2*)&Tl[ob + i * 4] = pl;
  }
}

// ---------------- MFMA flash attention, Q-COMPACT (bf16x3 QK + PV) -----------
// Block = 64 COMPACT queries (batch-uniform by scan2 construction) x head.
// Q gathered via sTok; causal qpos = tok&2047; ctx written COMPACT rows.
__global__ __launch_bounds__(256) void attn_mfma(
    const u16* __restrict__ Qh, const u16* __restrict__ Ql,
    const u16* __restrict__ Kh2, const u16* __restrict__ Kl2,
    const u16* __restrict__ VTh, const u16* __restrict__ VTl,
    const int* __restrict__ cidx2,
    u16* __restrict__ ctxH, u16* __restrict__ ctxL) {
  int blk = (int)gridDim.x - 1 - (int)blockIdx.x;  // heavier blocks first
  int q0c = blk * 64, hh = blockIdx.y;
  int t = threadIdx.x;
  int lane = t & 63, w = t >> 6;
  int kvh = hh >> 2;
  __shared__ __align__(16) char sQh[8192], sQl[8192];
  __shared__ __align__(16) char sKh[8192], sKl[8192];
  __shared__ __align__(16) char sVh[8192], sVl[8192];
  __shared__ __align__(16) char sPh[8192], sPl[8192];
  __shared__ int sTok[64];
  if (t < 64) sTok[t] = cidx2[q0c + t];
  __syncthreads();
  int b = sTok[0] >> 11;                  // batch-uniform per block (scan2)
  int ntiles = ((sTok[63] & (kS - 1)) >> 6) + 1;   // ascending per segment
#pragma unroll
  for (int p = 0; p < 4; ++p) {
    int idx = t + p * 256;
    int r = idx >> 4, kc = idx & 15;
    int off = r * 128 + ((kc * 8) ^ ((r & 7) << 4));
    size_t gq = (size_t)sTok[r] * (kH * kDH) + hh * kDH + kc * 4;
    *(uint2*)(sQh + off) = *(const uint2*)&Qh[gq];
    *(uint2*)(sQl + off) = *(const uint2*)&Ql[gq];
  }
  f32x4 ctxa[4];
#pragma unroll
  for (int i = 0; i < 4; ++i) ctxa[i] = {0.f, 0.f, 0.f, 0.f};
  float lsum[4] = {0.f, 0.f, 0.f, 0.f};
  for (int kt = 0; kt < ntiles; ++kt) {
    __syncthreads();
#pragma unroll
    for (int p = 0; p < 4; ++p) {
      int idx = t + p * 256;
      int r = idx >> 4, kc = idx & 15;
      int off = r * 128 + ((kc * 8) ^ ((r & 7) << 4));
      size_t gk = (size_t)(b * kS + kt * 64 + r) * (kKV * kDH) + kvh * kDH + kc * 4;
      size_t gv = ((size_t)(b * kKV + kvh) * kDH + r) * kS + kt * 64 + kc * 4;
      *(uint2*)(sKh + off) = *(const uint2*)&Kh2[gk];
      *(uint2*)(sKl + off) = *(const uint2*)&Kl2[gk];
      *(uint2*)(sVh + off) = *(const uint2*)&VTh[gv];
      *(uint2*)(sVl + off) = *(const uint2*)&VTl[gv];
    }
    __syncthreads();
    f32x4 sf[4];
#pragma unroll
    for (int i = 0; i < 4; ++i) sf[i] = {0.f, 0.f, 0.f, 0.f};
#pragma unroll
    for (int ks = 0; ks < 2; ++ks) {
      int m = w * 16 + (lane & 15);
      int kb = ks * 64 + ((lane >> 4) << 4);
      int ao = m * 128 + (kb ^ ((m & 7) << 4));
      bf16x8 qh8 = *(bf16x8*)(sQh + ao);
      bf16x8 ql8 = *(bf16x8*)(sQl + ao);
#pragma unroll
      for (int nf = 0; nf < 4; ++nf) {
        int n = nf * 16 + (lane & 15);
        int bo = n * 128 + (kb ^ ((n & 7) << 4));
        bf16x8 kh8 = *(bf16x8*)(sKh + bo);
        bf16x8 kl8 = *(bf16x8*)(sKl + bo);
        sf[nf] = __builtin_amdgcn_mfma_f32_16x16x32_bf16(qh8, kh8, sf[nf], 0, 0, 0);
        sf[nf] = __builtin_amdgcn_mfma_f32_16x16x32_bf16(qh8, kl8, sf[nf], 0, 0, 0);
        sf[nf] = __builtin_amdgcn_mfma_f32_16x16x32_bf16(ql8, kh8, sf[nf], 0, 0, 0);
      }
    }
    int qrow = (lane >> 4) << 2;
    int qp[4];
#pragma unroll
    for (int rg = 0; rg < 4; ++rg) qp[rg] = sTok[w * 16 + qrow + rg] & (kS - 1);
#pragma unroll
    for (int nf = 0; nf < 4; ++nf) {
      int key = kt * 64 + nf * 16 + (lane & 15);
#pragma unroll
      for (int rg = 0; rg < 4; ++rg) {
        float p = 0.f;
        if (key <= qp[rg]) p = __expf(sf[nf][rg] * 0.125f);
        lsum[rg] += p;
        u32 ph, pl;
        splitbf(p, ph, pl);
        int ql_ = w * 16 + qrow + rg;
        int kl_ = nf * 16 + (lane & 15);
        int po = ql_ * 128 + ((kl_ * 2) ^ ((ql_ & 7) << 4));
        *(u16*)(sPh + po) = (u16)ph;
        *(u16*)(sPl + po) = (u16)pl;
      }
    }
#pragma unroll
    for (int ks = 0; ks < 2; ++ks) {
      int m = w * 16 + (lane & 15);
      int kb = ks * 64 + ((lane >> 4) << 4);
      int ao = m * 128 + (kb ^ ((m & 7) << 4));
      bf16x8 ph8 = *(bf16x8*)(sPh + ao);
      bf16x8 pl8 = *(bf16x8*)(sPl + ao);
#pragma unroll
      for (int nf = 0; nf < 4; ++nf) {
        int n = nf * 16 + (lane & 15);
        int bo = n * 128 + (kb ^ ((n & 7) << 4));
        bf16x8 vh8 = *(bf16x8*)(sVh + bo);
        bf16x8 vl8 = *(bf16x8*)(sVl + bo);
        ctxa[nf] = __builtin_amdgcn_mfma_f32_16x16x32_bf16(ph8, vh8, ctxa[nf], 0, 0, 0);
        ctxa[nf] = __builtin_amdgcn_mfma_f32_16x16x32_bf16(ph8, vl8, ctxa[nf], 0, 0, 0);
        ctxa[nf] = __builtin_amdgcn_mfma_f32_16x16x32_bf16(pl8, vh8, ctxa[nf], 0, 0, 0);
      }
    }
  }
#pragma unroll
  for (int rg = 0; rg < 4; ++rg) {
    float ps = lsum[rg];
    ps += __shfl_xor(ps, 1); ps += __shfl_xor(ps, 2);
    ps += __shfl_xor(ps, 4); ps += __shfl_xor(ps, 8);
    lsum[rg] = ps;
  }
#pragma unroll
  for (int nf = 0; nf < 4; ++nf) {
    int d = nf * 16 + (lane & 15);
#pragma unroll
    for (int rg = 0; rg < 4; ++rg) {
      int crow = q0c + w * 16 + ((lane >> 4) << 2) + rg;    // COMPACT row
      float cv = ctxa[nf][rg] / lsum[rg];
      u32 ch, cl;
      splitbf(cv, ch, cl);
      size_t co = (size_t)crow * (kH * kDH) + hh * kDH + d;
      ctxH[co] = (u16)ch;
      ctxL[co] = (u16)cl;
    }
  }
}

// ---------------- silu(gu.g)*gu.u with fused split (fused-GU input) ----------
__global__ __launch_bounds__(256) void silu_mul_split_kernel(
    const float* __restrict__ gu, u16* __restrict__ hi, u16* __restrict__ lo,
    int keepR) {
  int i = blockIdx.x * 256 + threadIdx.x;
  int total = keepR * (kFI / 4);
  if (i >= total) return;
  int row = i / (kFI / 4);
  int c4 = (i - row * (kFI / 4)) * 4;
  float4 gv = *(const float4*)&gu[(size_t)row * kGU + c4];
  float4 uv = *(const float4*)&gu[(size_t)row * kGU + kFI + c4];
  float m0 = (gv.x / (1.f + expf(-gv.x))) * uv.x;
  float m1 = (gv.y / (1.f + expf(-gv.y))) * uv.y;
  float m2 = (gv.z / (1.f + expf(-gv.z))) * uv.z;
  float m3 = (gv.w / (1.f + expf(-gv.w))) * uv.w;
  u32 h0, h1, h2, h3, l0, l1, l2, l3;
  splitbf(m0, h0, l0); splitbf(m1, h1, l1);
  splitbf(m2, h2, l2); splitbf(m3, h3, l3);
  uint2 ph, pl;
  ph.x = h0 | (h1 << 16); ph.y = h2 | (h3 << 16);
  pl.x = l0 | (l1 << 16); pl.y = l2 | (l3 << 16);
  *(uint2*)&hi[(size_t)row * kFI + c4] = ph;
  *(uint2*)&lo[(size_t)row * kFI + c4] = pl;
}

// ---------------- weight transpose + split with dst stride/offset ------------
__global__ __launch_bounds__(256) void tsplit_kernel(const float* __restrict__ W,
    u16* __restrict__ Th, u16* __restrict__ Tl, int N, int K, size_t dstStride) {
  size_t mat = (size_t)blockIdx.z * (size_t)K * N;
  size_t dob = (size_t)blockIdx.z * dstStride;
  int n0 = blockIdx.x * 64, k0 = blockIdx.y * 64;
  __shared__ float T[64][65];
  int t = threadIdx.x;
#pragma unroll
  for (int p = 0; p < 16; ++p) {
    int idx = t + p * 256;
    int kl = idx >> 6, nl = idx & 63;
    T[nl][kl] = W[mat + (size_t)(k0 + kl) * N + n0 + nl];
  }
  __syncthreads();
  int nl = t >> 2, kg = t & 3;
  size_t ob = dob + (size_t)(n0 + nl) * K + k0 + kg * 16;
#pragma unroll
  for (int i = 0; i < 4; ++i) {
    int kk = kg * 16 + i * 4;
    u32 h0, h1, h2, h3, l0, l1, l2, l3;
    splitbf(T[nl][kk + 0], h0, l0); splitbf(T[nl][kk + 1], h1, l1);
    splitbf(T[nl][kk + 2], h2, l2); splitbf(T[nl][kk + 3], h3, l3);
    uint2 ph, pl;
    ph.x = h0 | (h1 << 16); ph.y = h2 | (h3 << 16);
    pl.x = l0 | (l1 << 16); pl.y = l2 | (l3 << 16);
    *(uint2*)&Th[ob + i * 4] = ph;
    *(uint2*)&Tl[ob + i * 4] = pl;
  }
}

// ---------------- weight transpose, hi only: W[K][N] -> Bt bf16 [N][K] -------
__global__ __launch_bounds__(256) void tconv_kernel(const float* __restrict__ W,
    u16* __restrict__ Bt, int N, int K) {
  int n0 = blockIdx.x * 64, k0 = blockIdx.y * 64;
  __shared__ float T[64][65];
  int t = threadIdx.x;
#pragma unroll
  for (int p = 0; p < 16; ++p) {
    int idx = t + p * 256;
    int kl = idx >> 6, nl = idx & 63;
    T[nl][kl] = W[(size_t)(k0 + kl) * N + n0 + nl];
  }
  __syncthreads();
  int nl = t >> 2, kg = t & 3;
  size_t ob = (size_t)(n0 + nl) * K + k0 + kg * 16;
#pragma unroll
  for (int i = 0; i < 4; ++i) {
    int kk = kg * 16 + i * 4;
    uint2 ph;
    ph.x = f2bf1(T[nl][kk + 0]) | (f2bf1(T[nl][kk + 1]) << 16);
    ph.y = f2bf1(T[nl][kk + 2]) | (f2bf1(T[nl][kk + 3]) << 16);
    *(uint2*)&Bt[ob + i * 4] = ph;
  }
}

// ---------------- bf16x3 MFMA GEMM (global_load_lds staging) -----------------
// MODE 0: C=A@B            MODE 3: COMPACT->scatter: C[gidx[r]] = acc + Add[r]
// MODE 4: gathered-residual: C[r] = acc + Add[gidx[r]]   (gidx via `mask`)
template <int MODE>
__global__ __launch_bounds__(256) void gemm_bf3(
    const u16* __restrict__ Ah, const u16* __restrict__ Al,
    const u16* __restrict__ Bh, const u16* __restrict__ Bl,
    float* __restrict__ C, int N, int K,
    const float* __restrict__ Add, const int* __restrict__ mask, int gridR) {
  __shared__ __align__(16) char AsH[16384];
  __shared__ __align__(16) char AsL[16384];
  __shared__ __align__(16) char BsH[16384];
  __shared__ __align__(16) char BsL[16384];
  int t = threadIdx.x;
  int lane = t & 63, w = t >> 6;
  int wr = w >> 1, wc = w & 1;
  int lid = xcd_remap((int)blockIdx.x, (int)gridDim.x);
  int row0 = (lid % gridR) * 128, col0 = (lid / gridR) * 128;
  f32x4 acc[4][4];
#pragma unroll
  for (int i = 0; i < 4; ++i)
#pragma unroll
    for (int j = 0; j < 4; ++j) acc[i][j] = {0.f, 0.f, 0.f, 0.f};

  for (int k0 = 0; k0 < K; k0 += 64) {
    stage_lds16(Ah, K, row0, k0, AsH, t);
    stage_lds16(Al, K, row0, k0, AsL, t);
    stage_lds16(Bh, K, col0, k0, BsH, t);
    stage_lds16(Bl, K, col0, k0, BsL, t);
    __syncthreads();
#pragma unroll
    for (int ks = 0; ks < 2; ++ks) {
      bf16x8 ah[4], al4[4], bh[4], bl4[4];
      int kb = ks * 64 + ((lane >> 4) << 4);
#pragma unroll
      for (int i = 0; i < 4; ++i) {
        int m = wr * 64 + i * 16 + (lane & 15);
        int n = wc * 64 + i * 16 + (lane & 15);
        int ao = m * 128 + (kb ^ ((m & 7) << 4));
        int bo = n * 128 + (kb ^ ((n & 7) << 4));
        ah[i] = *(bf16x8*)(AsH + ao);
        al4[i] = *(bf16x8*)(AsL + ao);
        bh[i] = *(bf16x8*)(BsH + bo);
        bl4[i] = *(bf16x8*)(BsL + bo);
      }
#pragma unroll
      for (int mb = 0; mb < 4; ++mb)
#pragma unroll
        for (int nb = 0; nb < 4; ++nb) {
          acc[mb][nb] = __builtin_amdgcn_mfma_f32_16x16x32_bf16(
              ah[mb], bh[nb], acc[mb][nb], 0, 0, 0);
          acc[mb][nb] = __builtin_amdgcn_mfma_f32_16x16x32_bf16(
              ah[mb], bl4[nb], acc[mb][nb], 0, 0, 0);
          acc[mb][nb] = __builtin_amdgcn_mfma_f32_16x16x32_bf16(
              al4[mb], bh[nb], acc[mb][nb], 0, 0, 0);
        }
    }
    __syncthreads();
  }
#pragma unroll
  for (int mb = 0; mb < 4; ++mb) {
    int rb = row0 + wr * 64 + mb * 16 + ((lane >> 4) << 2);
#pragma unroll
    for (int rg = 0; rg < 4; ++rg) {
      int r = rb + rg;
      int wrow = r, arow = r;
      if (MODE == 3) wrow = mask[r];      // scatter; Add stays compact (r)
      if (MODE == 4) arow = mask[r];      // gathered residual; write compact
#pragma unroll
      for (int nb = 0; nb < 4; ++nb) {
        int c = col0 + wc * 64 + nb * 16 + (lane & 15);
        float vv = acc[mb][nb][rg];
        if (MODE == 3) vv += Add[(size_t)r * N + c];
        if (MODE == 4) vv += Add[(size_t)arow * N + c];
        C[(size_t)wrow * N + c] = vv;
      }
    }
  }
}

// ---------------- lm_head fast: gload_lds staging + A-supertile ordering -----
__global__ __launch_bounds__(256) void lmhead_fast(const u16* __restrict__ Abf,
    const u16* __restrict__ Bt, float* __restrict__ C, int N, int K, int gridR) {
  __shared__ __align__(16) char AsB[16384];
  __shared__ __align__(16) char BsB[16384];
  int t = threadIdx.x;
  int lane = t & 63, w = t >> 6;
  int wr = w >> 1, wc = w & 1;
  int lid = xcd_remap((int)blockIdx.x, (int)gridDim.x);
  int panels = (int)gridDim.x / gridR;
  const int RG = 14;
  int fullg = gridR / RG;
  int lastr = gridR - fullg * RG;
  int fgb = fullg * RG * panels;
  int row, panel;
  if (lid < fgb) {
    int g = lid / (RG * panels);
    int r2 = lid % (RG * panels);
    row = g * RG + (r2 % RG);
    panel = r2 / RG;
  } else {
    int r2 = lid - fgb;
    row = fullg * RG + (r2 % lastr);
    panel = r2 / lastr;
  }
  int row0 = row * 128, col0 = panel * 128;
  f32x4 acc[4][4];
#pragma unroll
  for (int i = 0; i < 4; ++i)
#pragma unroll
    for (int j = 0; j < 4; ++j) acc[i][j] = {0.f, 0.f, 0.f, 0.f};

  for (int k0 = 0; k0 < K; k0 += 64) {
    stage_lds16(Abf, K, row0, k0, AsB, t);
    stage_lds16(Bt, K, col0, k0, BsB, t);
    __syncthreads();
#pragma unroll
    for (int ks = 0; ks < 2; ++ks) {
      bf16x8 af[4], bfr[4];
      int kb = ks * 64 + ((lane >> 4) << 4);
#pragma unroll
      for (int i = 0; i < 4; ++i) {
        int m = wr * 64 + i * 16 + (lane & 15);
        int n = wc * 64 + i * 16 + (lane & 15);
        af[i] = *(bf16x8*)(AsB + m * 128 + (kb ^ ((m & 7) << 4)));
        bfr[i] = *(bf16x8*)(BsB + n * 128 + (kb ^ ((n & 7) << 4)));
      }
#pragma unroll
      for (int mb = 0; mb < 4; ++mb)
#pragma unroll
        for (int nb = 0; nb < 4; ++nb)
          acc[mb][nb] = __builtin_amdgcn_mfma_f32_16x16x32_bf16(
              af[mb], bfr[nb], acc[mb][nb], 0, 0, 0);
    }
    __syncthreads();
  }
#pragma unroll
  for (int mb = 0; mb < 4; ++mb) {
    int row2 = row0 + wr * 64 + mb * 16 + ((lane >> 4) << 2);
#pragma unroll
    for (int nb = 0; nb < 4; ++nb) {
      int col = col0 + wc * 64 + nb * 16 + (lane & 15);
#pragma unroll
      for (int rg = 0; rg < 4; ++rg)
        __builtin_nontemporal_store(acc[mb][nb][rg],
                                    &C[(size_t)(row2 + rg) * N + col]);
    }
  }
}

// ---------------- lm_head hybrid tail: A bf16 (ws) x B f32 via coalesced LDS -
__global__ __launch_bounds__(256) void lmhead_hyb(const u16* __restrict__ Abf2,
    const float* __restrict__ Bm, float* __restrict__ C, int N, int K, int gridR) {
  __shared__ __align__(16) char AsB[16384];
  __shared__ __align__(16) char BsB[16384];
  __shared__ float sBf[64][132];
  int t = threadIdx.x;
  int lane = t & 63, w = t >> 6;
  int wr = w >> 1, wc = w & 1;
  int lid = xcd_remap((int)blockIdx.x, (int)gridDim.x);
  int row0 = (lid % gridR) * 128, col0 = (lid / gridR) * 128;
  f32x4 acc[4][4];
#pragma unroll
  for (int i = 0; i < 4; ++i)
#pragma unroll
    for (int j = 0; j < 4; ++j) acc[i][j] = {0.f, 0.f, 0.f, 0.f};

  for (int k0 = 0; k0 < K; k0 += 64) {
    stage_lds16(Abf2, K, row0, k0, AsB, t);
#pragma unroll
    for (int p = 0; p < 8; ++p) {
      int idx = t + p * 256;
      int kk = idx >> 5, c4 = (idx & 31) << 2;
      *(float4*)&sBf[kk][c4] = *(const float4*)&Bm[(size_t)(k0 + kk) * N + col0 + c4];
    }
    __syncthreads();
#pragma unroll
    for (int p = 0; p < 4; ++p) {
      int nl = t & 127;
      int kb = ((t >> 7) << 3) + p * 16;
      unsigned pk[4];
#pragma unroll
      for (int j = 0; j < 4; ++j)
        pk[j] = f2bf1(sBf[kb + 2 * j][nl]) | (f2bf1(sBf[kb + 2 * j + 1][nl]) << 16);
      uint4 w4; w4.x = pk[0]; w4.y = pk[1]; w4.z = pk[2]; w4.w = pk[3];
      *(uint4*)(BsB + nl * 128 + ((kb * 2) ^ ((nl & 7) << 4))) = w4;
    }
    __syncthreads();
#pragma unroll
    for (int ks = 0; ks < 2; ++ks) {
      bf16x8 af[4], bfr[4];
      int kb = ks * 64 + ((lane >> 4) << 4);
#pragma unroll
      for (int i = 0; i < 4; ++i) {
        int m = wr * 64 + i * 16 + (lane & 15);
        int n = wc * 64 + i * 16 + (lane & 15);
        af[i] = *(bf16x8*)(AsB + m * 128 + (kb ^ ((m & 7) << 4)));
        bfr[i] = *(bf16x8*)(BsB + n * 128 + (kb ^ ((n & 7) << 4)));
      }
#pragma unroll
      for (int mb = 0; mb < 4; ++mb)
#pragma unroll
        for (int nb = 0; nb < 4; ++nb)
          acc[mb][nb] = __builtin_amdgcn_mfma_f32_16x16x32_bf16(
              af[mb], bfr[nb], acc[mb][nb], 0, 0, 0);
    }
    __syncthreads();
  }
#pragma unroll
  for (int mb = 0; mb < 4; ++mb) {
    int row = row0 + wr * 64 + mb * 16 + ((lane >> 4) << 2);
#pragma unroll
    for (int nb = 0; nb < 4; ++nb) {
      int col = col0 + wc * 64 + nb * 16 + (lane & 15);
#pragma unroll
      for (int rg = 0; rg < 4; ++rg)
        __builtin_nontemporal_store(acc[mb][nb][rg],
                                    &C[(size_t)(row + rg) * N + col]);
    }
  }
}

__global__ __launch_bounds__(256) void copy_kernel(const float* __restrict__ src,
    float* __restrict__ dst, int n) {
  int i = blockIdx.x * 256 + threadIdx.x;
  if (i < n) dst[i] = src[i];
}

__global__ void finish_kernel(const float* __restrict__ aux, float* __restrict__ dst) {
  dst[0] = aux[0];
}

// ---------------- orchestration ---------------------------------------------
extern "C" void kernel_launch(void* const* d_in, const int* in_sizes, int n_in,
                              void* d_out, int out_size, void* d_ws, size_t ws_size,
                              hipStream_t stream) {
  const int* ids = (const int*)d_in[0];
  const float* emb = (const float*)d_in[1];
  const float* Wq = (const float*)d_in[2];
  const float* Wk = (const float*)d_in[3];
  const float* Wv = (const float*)d_in[4];
  const float* Wo = (const float*)d_in[5];
  const float* Wg = (const float*)d_in[6];
  const float* Wu = (const float*)d_in[7];
  const float* Wd = (const float*)d_in[8];
  const float* n1 = (const float*)d_in[9];
  const float* n2 = (const float*)d_in[10];
  const float* rw = (const float*)d_in[11];
  const float* fn = (const float*)d_in[12];
  const float* lmh = (const float*)d_in[13];
  float* out = (float*)d_out;

  // --- d_ws (~1.82 MiB) ---
  float* ws = (float*)d_ws;
  size_t woff = 0;
  float* cosT = ws + woff;   woff += (size_t)kS * 32;
  float* sinT = ws + woff;   woff += (size_t)kS * 32;
  float* scores = ws + woff; woff += kT;
  float* aux = ws + woff;    woff += 4;
  int* mask = (int*)(ws + woff); woff += kT;
  int* cidx2 = (int*)(ws + woff); woff += kT;
  u16* Abf2 = (u16*)(ws + woff);  // (kT-kR1)*kD u16

  // --- d_out layout: front scratch | x | Abf | Bt (tail) ---
  float* x = out + kXOff;
  u16* Abf = (u16*)(out + kAbfOff);
  u16* Bt = (u16*)(out + kBtOff);
  size_t off = 0;
  auto alloc = [&](size_t n) { float* p = out + off; off += n; return p; };
  float* qkv  = alloc((size_t)kT * kQKV);     // fused q|k|v f32
  float* xa   = alloc((size_t)kT * kD);       // COMPACT rows
  float* gu   = alloc((size_t)kT * kGU);      // fused g|u f32 (compact)
  u16* hH   = (u16*)alloc((size_t)kT * kD / 2);
  u16* hL   = (u16*)alloc((size_t)kT * kD / 2);
  u16* ctxH = (u16*)alloc((size_t)kT * kD / 2);   // COMPACT rows
  u16* ctxL = (u16*)alloc((size_t)kT * kD / 2);
  u16* mmH  = (u16*)alloc((size_t)kT * kFI / 2);
  u16* mmL  = (u16*)alloc((size_t)kT * kFI / 2);
  u16* QhB  = (u16*)alloc((size_t)kT * kH * kDH / 2);
  u16* QlB  = (u16*)alloc((size_t)kT * kH * kDH / 2);
  u16* KhB  = (u16*)alloc((size_t)kT * kKV * kDH / 2);
  u16* KlB  = (u16*)alloc((size_t)kT * kKV * kDH / 2);
  u16* VTh  = (u16*)alloc((size_t)kT * kKV * kDH / 2);
  u16* VTl  = (u16*)alloc((size_t)kT * kKV * kDH / 2);
  u16* WqkvH = (u16*)alloc(1572864); u16* WqkvL = (u16*)alloc(1572864);
  u16* WoH   = (u16*)alloc(1048576); u16* WoL   = (u16*)alloc(1048576);
  u16* WguH  = (u16*)alloc(5767168); u16* WguL  = (u16*)alloc(5767168);
  u16* WdH   = (u16*)alloc(2883584); u16* WdL   = (u16*)alloc(2883584);
  (void)in_sizes; (void)n_in; (void)ws_size;

  tables_kernel<<<kS * 32 / 256, 256, 0, stream>>>(cosT, sinT);
  init_kernel<<<1, 256, 0, stream>>>(mask, aux);
  embed_kernel<<<kT, 256, 0, stream>>>(ids, emb, x);

  const size_t sQKV = (size_t)kQKV * kD;
  const size_t sGU = (size_t)kGU * kD;
  tsplit_kernel<<<dim3(16, 16, 2), 256, 0, stream>>>(
      Wq, WqkvH, WqkvL, 1024, 1024, sQKV);
  tsplit_kernel<<<dim3(4, 16, 2), 256, 0, stream>>>(
      Wk, WqkvH + 1024 * 1024, WqkvL + 1024 * 1024, 256, 1024, sQKV);
  tsplit_kernel<<<dim3(4, 16, 2), 256, 0, stream>>>(
      Wv, WqkvH + 1280 * 1024, WqkvL + 1280 * 1024, 256, 1024, sQKV);
  tsplit_kernel<<<dim3(16, 16, 2), 256, 0, stream>>>(
      Wo, WoH, WoL, 1024, 1024, (size_t)1024 * 1024);
  tsplit_kernel<<<dim3(44, 16, 2), 256, 0, stream>>>(
      Wg, WguH, WguL, 2816, 1024, sGU);
  tsplit_kernel<<<dim3(44, 16, 2), 256, 0, stream>>>(
      Wu, WguH + 2816 * 1024, WguL + 2816 * 1024, 2816, 1024, sGU);
  tsplit_kernel<<<dim3(16, 44, 2), 256, 0, stream>>>(
      Wd, WdH, WdL, 1024, 2816, (size_t)2816 * 1024);
  tconv_kernel<<<dim3(kV / 64, kD / 64), 256, 0, stream>>>(lmh, Bt, kV, kD);

  const int keeps[3]  = {2744, 1838, 1231};  // int(n*0.67) chain from 4096
  const int keepR2[3] = {2944, 2048, 1408};  // >= keep+126, 128-multiple
  const int nt2[3]    = {23, 16, 11};        // keepR2/128
  for (int step = 0; step < 3; ++step) {
    int blk = step % 2;
    int keep = keeps[step], kr2 = keepR2[step], nt = nt2[step];
    int ablocks = kr2 / 64;
    size_t qkvo = (size_t)blk * sQKV;
    size_t oo = (size_t)blk * (kH * kDH) * kD;
    size_t guo = (size_t)blk * sGU;
    size_t dofs = (size_t)blk * kFI * kD;
    router_kernel<<<kT, 64, 0, stream>>>(x, rw, scores);
    topk_kernel<<<1, 1024, 0, stream>>>(scores, mask, aux, keep);
    scan2_kernel<<<1, 1024, 0, stream>>>(mask, cidx2, kr2);
    rmsnorm_split_kernel<<<kT, 256, 0, stream>>>(x, n1 + (size_t)blk * kD, hH, hL);
    gemm_bf3<0><<<32 * 12, 256, 0, stream>>>(
        hH, hL, WqkvH + qkvo, WqkvL + qkvo, qkv, kQKV, kD, nullptr, nullptr, 32);
    rope_split_kernel<<<(kT * kH * 32 + kT * kKV * 32) / 256, 256, 0, stream>>>(
        qkv, cosT, sinT, QhB, QlB, KhB, KlB);
    vtsplit_kernel<<<dim3(kS / 64, kKV, kB), 256, 0, stream>>>(qkv, VTh, VTl);
    attn_mfma<<<dim3(ablocks, kH), 256, 0, stream>>>(
        QhB, QlB, KhB, KlB, VTh, VTl, cidx2, ctxH, ctxL);
    // Wo over COMPACT rows; residual gathered from full x via cidx2
    gemm_bf3<4><<<nt * 8, 256, 0, stream>>>(
        ctxH, ctxL, WoH + oo, WoL + oo, xa, kD, kH * kDH, x, cidx2, nt);
    // compact MLP chain
    rmsnorm_split_kernel<<<kr2, 256, 0, stream>>>(
        xa, n2 + (size_t)blk * kD, hH, hL);
    gemm_bf3<0><<<nt * 44, 256, 0, stream>>>(
        hH, hL, WguH + guo, WguL + guo, gu, kGU, kD, nullptr, nullptr, nt);
    silu_mul_split_kernel<<<(kr2 * (kFI / 4) + 255) / 256, 256, 0, stream>>>(
        gu, mmH, mmL, kr2);
    gemm_bf3<3><<<nt * 8, 256, 0, stream>>>(
        mmH, mmL, WdH + dofs, WdL + dofs, x, kD, kFI, xa, cidx2, nt);
  }

  // lm_head
  finalnorm_conv<<<kT, 256, 0, stream>>>(x, fn, Abf);
  copy_kernel<<<(kT - kR1) * kD / 2 / 256, 256, 0, stream>>>(
      (const float*)(Abf + (size_t)kR1 * kD), (float*)Abf2, (kT - kR1) * kD / 2);
  lmhead_fast<<<(kR1 / 128) * (kV / 128), 256, 0, stream>>>(
      Abf, Bt, out, kV, kD, kR1 / 128);
  lmhead_hyb<<<((kT - kR1) / 128) * (kV / 128), 256, 0, stream>>>(
      Abf2, lmh, out + (size_t)kR1 * kV, kV, kD, (kT - kR1) / 128);
  finish_kernel<<<1, 1, 0, stream>>>(aux, out + (size_t)out_size - 1);
}